// Round 10
// baseline (244.653 us; speedup 1.0000x reference)
//
#include <hip/hip_runtime.h>

#define N_NODES 10000
#define N_EDGES 320000
#define DIN 512
#define DHID 512
#define DOUT 256

typedef __bf16 bf16x8 __attribute__((ext_vector_type(8)));
typedef float f32x4 __attribute__((ext_vector_type(4)));
typedef unsigned short ushort_t;
typedef unsigned int uint_t;

__device__ __forceinline__ float b2f(ushort_t u){
    union { uint_t i; float f; } v; v.i = (uint_t)u << 16; return v.f;
}
__device__ __forceinline__ float blo(uint_t v){
    union { uint_t i; float f; } u; u.i = v << 16; return u.f;
}
__device__ __forceinline__ float bhi(uint_t v){
    union { uint_t i; float f; } u; u.i = v & 0xffff0000u; return u.f;
}
__device__ __forceinline__ ushort_t f2b(float f){
    union { float f; uint_t i; } v; v.f = f;
    uint_t i = v.i;
    return (ushort_t)((i + 0x7fffu + ((i >> 16) & 1u)) >> 16); // RNE
}

__device__ __forceinline__ void gll16(const ushort_t* g, ushort_t* l){
    __builtin_amdgcn_global_load_lds(
        (const __attribute__((address_space(1))) unsigned int*)g,
        (__attribute__((address_space(3))) unsigned int*)l,
        16, 0, 0);
}

// ---------------- CSR build ----------------

// zero degree array + the 1KB zero-row page used for edge padding
__global__ void k_zero(int* __restrict__ deg, uint_t* __restrict__ zp){
    int i = blockIdx.x * 256 + threadIdx.x;
    if (i < N_NODES) deg[i] = 0;
    if (i < 256) zp[i] = 0u;
}

__global__ void k_degree(const int* __restrict__ dst, int* __restrict__ deg){
    int e = blockIdx.x * 256 + threadIdx.x;
    if (e < N_EDGES) atomicAdd(&deg[dst[e]], 1);
}

// 256 threads, 40 elems/thread serial scan in regs + 8-round block scan.
__global__ void k_scan(const int* __restrict__ deg, int* __restrict__ row_ptr,
                       int* __restrict__ cursor){
    __shared__ int part[256];
    int t = threadIdx.x;
    int base = t * 40;
    int loc[40];
    int s = 0;
    #pragma unroll
    for (int i = 0; i < 40; ++i){
        int idx = base + i;
        int v = (idx < N_NODES) ? deg[idx] : 0;
        s += v; loc[i] = s;          // thread-local inclusive
    }
    part[t] = s;
    __syncthreads();
    int val = s;
    for (int off = 1; off < 256; off <<= 1){
        int x = (t >= off) ? part[t - off] : 0;
        __syncthreads();
        val += x; part[t] = val;
        __syncthreads();
    }
    int exc = val - s;               // exclusive prefix of this thread's chunk
    if (t == 0) row_ptr[0] = 0;
    int run = exc;
    #pragma unroll
    for (int i = 0; i < 40; ++i){
        int idx = base + i;
        if (idx < N_NODES){
            row_ptr[idx + 1] = exc + loc[i];
            cursor[idx] = run;       // bucket start (exclusive)
        }
        run = exc + loc[i];
    }
}

__global__ void k_scatter(const int* __restrict__ src, const int* __restrict__ dst,
                          int* __restrict__ cursor, int* __restrict__ srcs){
    int e = blockIdx.x * 256 + threadIdx.x;
    if (e < N_EDGES){
        int p = atomicAdd(&cursor[dst[e]], 1);
        srcs[p] = src[e];
    }
}

// ---------------- weight f32 -> bf16 conversion (once per call) ----------------

struct CvtArgs { const float* s[9]; ushort_t* d[9]; int n[9]; };

__global__ void k_cvt(CvtArgs a){
    int m = blockIdx.y;
    int i = (blockIdx.x * 256 + threadIdx.x) * 8;
    if (i < a.n[m]){
        const float* sp = a.s[m] + i;
        float4 f0 = *(const float4*)sp;
        float4 f1 = *(const float4*)(sp + 4);
        uint4 u;
        u.x = (uint_t)f2b(f0.x) | ((uint_t)f2b(f0.y) << 16);
        u.y = (uint_t)f2b(f0.z) | ((uint_t)f2b(f0.w) << 16);
        u.z = (uint_t)f2b(f1.x) | ((uint_t)f2b(f1.y) << 16);
        u.w = (uint_t)f2b(f1.z) | ((uint_t)f2b(f1.w) << 16);
        *(uint4*)&a.d[m][i] = u;
    }
}

// ---------------- pe = w_pe^T + b_pe (LDS tile transpose, f32 -> bf16) ----------------

__global__ void k_pe(const float* __restrict__ w_pe, const float* __restrict__ b_pe,
                     ushort_t* __restrict__ h0){
    __shared__ float lt[64][68];  // [n_local][i_local], padded
    int t = threadIdx.x;
    int n0 = blockIdx.x * 64, i0 = blockIdx.y * 64;
    int nc = (t & 15) * 4, ir = t >> 4;   // ir 0..15
    #pragma unroll
    for (int p = 0; p < 4; ++p){
        int i_loc = ir + p * 16;
        float4 v = {0.f, 0.f, 0.f, 0.f};
        if (n0 + nc < N_NODES)
            v = *(const float4*)&w_pe[(size_t)(i0 + i_loc) * N_NODES + n0 + nc];
        lt[nc + 0][i_loc] = v.x;
        lt[nc + 1][i_loc] = v.y;
        lt[nc + 2][i_loc] = v.z;
        lt[nc + 3][i_loc] = v.w;
    }
    __syncthreads();
    int ic = t & 7, nr = t >> 3;   // nr 0..31
    #pragma unroll
    for (int p = 0; p < 2; ++p){
        int n_loc = nr + p * 32;
        int n = n0 + n_loc;
        if (n < N_NODES){
            uint4 u;
            uint_t w01 = (uint_t)f2b(lt[n_loc][ic*8+0] + b_pe[i0+ic*8+0])
                       | ((uint_t)f2b(lt[n_loc][ic*8+1] + b_pe[i0+ic*8+1]) << 16);
            uint_t w23 = (uint_t)f2b(lt[n_loc][ic*8+2] + b_pe[i0+ic*8+2])
                       | ((uint_t)f2b(lt[n_loc][ic*8+3] + b_pe[i0+ic*8+3]) << 16);
            uint_t w45 = (uint_t)f2b(lt[n_loc][ic*8+4] + b_pe[i0+ic*8+4])
                       | ((uint_t)f2b(lt[n_loc][ic*8+5] + b_pe[i0+ic*8+5]) << 16);
            uint_t w67 = (uint_t)f2b(lt[n_loc][ic*8+6] + b_pe[i0+ic*8+6])
                       | ((uint_t)f2b(lt[n_loc][ic*8+7] + b_pe[i0+ic*8+7]) << 16);
            u.x = w01; u.y = w23; u.z = w45; u.w = w67;
            *(uint4*)&h0[(size_t)n * DIN + i0 + ic * 8] = u;
        }
    }
}

// ---------------- mean aggregation v5: readlane + 256-dim panels ----------------
// grid (2500, 2): blockIdx.y = 256-dim panel. wave = one node; lane covers 4 dims
// (8B) -> one 512B coalesced gather per edge per panel (2 VMEM/edge total, was 4).
// Indices bulk-loaded 64-at-a-time; extracted per-edge with v_readlane (pure VALU).
// Ragged tail padded with `dummy` = index of a zeroed 1KB row (exact, adds 0).

#define AGG_EDGE(e, CH) { \
    int s_ = __builtin_amdgcn_readlane(sr, (e)); \
    uint2 v_ = *(const uint2*)&X[((size_t)(uint_t)s_ << 9) + col]; \
    CH##0 += blo(v_.x); CH##1 += bhi(v_.x); CH##2 += blo(v_.y); CH##3 += bhi(v_.y); }

__global__ __launch_bounds__(256) void k_agg(
    const ushort_t* __restrict__ X, const int* __restrict__ row_ptr,
    const int* __restrict__ srcs, ushort_t* __restrict__ out, int dummy)
{
    int w = threadIdx.x >> 6, lane = threadIdx.x & 63;
    int n = blockIdx.x * 4 + w;
    int col = blockIdx.y * 256 + lane * 4;
    int beg = row_ptr[n], end = row_ptr[n + 1];
    int deg = end - beg;
    float a0=0.f,a1=0.f,a2=0.f,a3=0.f;
    float p0=0.f,p1=0.f,p2=0.f,p3=0.f;
    float c0=0.f,c1=0.f,c2=0.f,c3=0.f;
    float d0=0.f,d1=0.f,d2=0.f,d3=0.f;

    for (int base = beg; base < end; base += 64){
        int rem = end - base;
        int sr = (lane < rem) ? srcs[base + lane] : dummy;
        int cnt = rem < 64 ? rem : 64;
        #pragma unroll
        for (int k = 0; k < 4; ++k){
            if (k * 16 < cnt){
                int L = k * 16;
                AGG_EDGE(L + 0,  a) AGG_EDGE(L + 1,  p) AGG_EDGE(L + 2,  c) AGG_EDGE(L + 3,  d)
                AGG_EDGE(L + 4,  a) AGG_EDGE(L + 5,  p) AGG_EDGE(L + 6,  c) AGG_EDGE(L + 7,  d)
                AGG_EDGE(L + 8,  a) AGG_EDGE(L + 9,  p) AGG_EDGE(L + 10, c) AGG_EDGE(L + 11, d)
                AGG_EDGE(L + 12, a) AGG_EDGE(L + 13, p) AGG_EDGE(L + 14, c) AGG_EDGE(L + 15, d)
            }
        }
    }

    float r0 = (a0 + p0) + (c0 + d0);
    float r1 = (a1 + p1) + (c1 + d1);
    float r2 = (a2 + p2) + (c2 + d2);
    float r3 = (a3 + p3) + (c3 + d3);
    float inv = (deg > 0) ? 1.f / (float)deg : 1.f;
    uint2 o;
    o.x = (uint_t)f2b(r0 * inv) | ((uint_t)f2b(r1 * inv) << 16);
    o.y = (uint_t)f2b(r2 * inv) | ((uint_t)f2b(r3 * inv) << 16);
    *(uint2*)&out[(size_t)n * 512 + col] = o;
}

// ---------------- fused SAGE layer: one-batch BM=160 geometry ----------------
// BM=160, BN=64, BK=32; 4 waves (2x2), wave tile 80x64 (5x2 MFMA blocks);
// LDS 64KB double-buffered -> 2 blocks/CU; one co-resident batch.
// Blocks sharing an m-tile land on the same XCD (bid%8 = m%8).
// Y(f32) = [leaky?](X@Ws^T + Agg@Wn^T + b) + X@Wr^T + rb

template<int DO, bool ACT, bool DUAL2, bool WRITE_BF>
__global__ __launch_bounds__(256, 2) void k_layer(
    const ushort_t* __restrict__ X, const ushort_t* __restrict__ G,
    const ushort_t* __restrict__ Ws, const ushort_t* __restrict__ Wn,
    const ushort_t* __restrict__ Wr,
    const float* __restrict__ b, const float* __restrict__ rb,
    float* __restrict__ Y, float* __restrict__ Y2, ushort_t* __restrict__ YB)
{
    // per 32KB buffer (ushort offsets): X:[0,5120) G:[5120,10240) Ws:[10240,12288)
    // Wn:[12288,14336) Wr:[14336,16384)  — rows of 32 elems (64B), linear for gll16
    __shared__ __align__(16) ushort_t smem[2][16384];

    int t = threadIdx.x;
    constexpr int NT = DO / 64;
    int bid = blockIdx.x;
    int r8 = bid & 7, q8 = bid >> 3;
    int m_t = (q8 / NT) * 8 + r8;
    int n_t = q8 % NT;
    if (m_t * 160 >= N_NODES) return;   // uniform whole-block guard
    int m0 = m_t * 160, n0 = n_t * 64;

    int lane = t & 63, w = t >> 6;
    int wr = w >> 1, wc = w & 1;        // wave tile: rows wr*80, cols wc*32

    // staging: 32 chunks of 1KB (16 rows x 64B), 8 per wave
    const ushort_t* gptr[8];
    int coff[8];
    int rl = lane >> 2, sl = (lane & 3) * 8;
    #pragma unroll
    for (int i = 0; i < 8; ++i){
        int qq = w * 8 + i;
        const ushort_t* gA; int rowbase, off;
        if (qq < 10)      { gA = X;  rowbase = m0 + qq * 16;        off = qq * 512; }
        else if (qq < 20) { gA = G;  rowbase = m0 + (qq - 10) * 16; off = 5120 + (qq - 10) * 512; }
        else if (qq < 24) { gA = Ws; rowbase = n0 + (qq - 20) * 16; off = 10240 + (qq - 20) * 512; }
        else if (qq < 28) { gA = Wn; rowbase = n0 + (qq - 24) * 16; off = 12288 + (qq - 24) * 512; }
        else              { gA = Wr; rowbase = n0 + (qq - 28) * 16; off = 14336 + (qq - 28) * 512; }
        gptr[i] = gA + (size_t)(rowbase + rl) * 512 + sl;
        coff[i] = off;   // wave-uniform; HW writes base + lane*16B
    }

    f32x4 accS[5][2] = {}, accG[5][2] = {}, accR[5][2] = {};
    int arow = wr * 80 + (lane & 15);
    int brow = wc * 32 + (lane & 15);
    int kk = (lane >> 4) * 8;

    // prologue: stage K-step 0 into buffer 0
    #pragma unroll
    for (int i = 0; i < 8; ++i) gll16(gptr[i], &smem[0][coff[i]]);
    __syncthreads();

    int cur = 0;
    for (int ks = 0; ks < 16; ++ks){
        if (ks < 15){
            int k0 = (ks + 1) * 32;
            #pragma unroll
            for (int i = 0; i < 8; ++i) gll16(gptr[i] + k0, &smem[cur ^ 1][coff[i]]);
        }

        const ushort_t* sb = smem[cur];
        bf16x8 ax[5], ag[5], bs[2], bn_[2], brr[2];
        #pragma unroll
        for (int m = 0; m < 5; ++m){
            ax[m] = *(const bf16x8*)&sb[(arow + m * 16) * 32 + kk];
            ag[m] = *(const bf16x8*)&sb[5120 + (arow + m * 16) * 32 + kk];
        }
        #pragma unroll
        for (int n = 0; n < 2; ++n){
            bs[n]  = *(const bf16x8*)&sb[10240 + (brow + n * 16) * 32 + kk];
            bn_[n] = *(const bf16x8*)&sb[12288 + (brow + n * 16) * 32 + kk];
            brr[n] = *(const bf16x8*)&sb[14336 + (brow + n * 16) * 32 + kk];
        }
        #pragma unroll
        for (int m = 0; m < 5; ++m)
            #pragma unroll
            for (int n = 0; n < 2; ++n){
                accS[m][n] = __builtin_amdgcn_mfma_f32_16x16x32_bf16(ax[m], bs[n],  accS[m][n], 0, 0, 0);
                accG[m][n] = __builtin_amdgcn_mfma_f32_16x16x32_bf16(ag[m], bn_[n], accG[m][n], 0, 0, 0);
                accR[m][n] = __builtin_amdgcn_mfma_f32_16x16x32_bf16(ax[m], brr[n], accR[m][n], 0, 0, 0);
            }

        __syncthreads();   // next buffer staged; all waves done reading cur
        cur ^= 1;
    }

    // epilogue: C/D layout col = lane&15, row = (lane>>4)*4 + reg
    int col_l = lane & 15;
    int row_l = (lane >> 4) * 4;
    #pragma unroll
    for (int n = 0; n < 2; ++n){
        int col = n0 + wc * 32 + n * 16 + col_l;
        float bb = b[col], rbb = rb[col];
        #pragma unroll
        for (int m = 0; m < 5; ++m){
            #pragma unroll
            for (int j = 0; j < 4; ++j){
                int row = m0 + wr * 80 + m * 16 + row_l + j;
                if (row < N_NODES){
                    float v = accS[m][n][j] + accG[m][n][j] + bb;
                    if (ACT) v = (v > 0.f) ? v : 0.01f * v;
                    v += accR[m][n][j] + rbb;
                    Y[(size_t)row * DO + col] = v;
                    if (DUAL2) Y2[(size_t)row * DO + col] = v;
                    if (WRITE_BF) YB[(size_t)row * DO + col] = f2b(v);
                }
            }
        }
    }
}

// ---------------- launch ----------------

extern "C" void kernel_launch(void* const* d_in, const int* in_sizes, int n_in,
                              void* d_out, int out_size, void* d_ws, size_t ws_size,
                              hipStream_t stream) {
    const int* edge  = (const int*)d_in[0];
    const int* e_src = edge;
    const int* e_dst = edge + N_EDGES;
    const float* w_pe = (const float*)d_in[1];
    const float* b_pe = (const float*)d_in[2];
    const float* ws0 = (const float*)d_in[3];
    const float* wn0 = (const float*)d_in[4];
    const float* b0  = (const float*)d_in[5];
    const float* wr0 = (const float*)d_in[6];
    const float* rb0 = (const float*)d_in[7];
    const float* ws1 = (const float*)d_in[8];
    const float* wn1 = (const float*)d_in[9];
    const float* b1  = (const float*)d_in[10];
    const float* wr1 = (const float*)d_in[11];
    const float* rb1 = (const float*)d_in[12];
    const float* ws2 = (const float*)d_in[13];
    const float* wn2 = (const float*)d_in[14];
    const float* b2  = (const float*)d_in[15];
    const float* wr2 = (const float*)d_in[16];
    const float* rb2 = (const float*)d_in[17];

    char* wsb = (char*)d_ws;
    ushort_t* h0   = (ushort_t*)wsb;                       // 10,240,000 B @ 0
    ushort_t* hb   = (ushort_t*)(wsb + 10240000);          // 10,240,000 B
    ushort_t* aggb = (ushort_t*)(wsb + 20480000);          // 10,240,000 B
    ushort_t* wbf  = (ushort_t*)(wsb + 30720000);          // 3,932,160 B
    int* deg     = (int*)(wsb + 34652160);                 // 10016 ints
    int* row_ptr = deg + 10016;
    int* cursor  = row_ptr + 10016;
    int* srcs    = cursor + 10016;                         // 320000 ints -> ends 36,052,352
    uint_t* zp   = (uint_t*)(wsb + 36052992);              // 1KB zero row (1024-aligned)
    // dummy row indices: (zp_off - buf_off) / 1024
    const int dummy_h0 = 35208;   // (36052992 - 0) / 1024
    const int dummy_hb = 25208;   // (36052992 - 10240000) / 1024

    ushort_t* wbf0s = wbf;
    ushort_t* wbf0n = wbf + 262144;
    ushort_t* wbf0r = wbf + 524288;
    ushort_t* wbf1s = wbf + 786432;
    ushort_t* wbf1n = wbf + 1048576;
    ushort_t* wbf1r = wbf + 1310720;
    ushort_t* wbf2s = wbf + 1572864;
    ushort_t* wbf2n = wbf + 1703936;
    ushort_t* wbf2r = wbf + 1835008;

    float* out  = (float*)d_out;
    float* fin  = out;               // [10000][256]
    float* mid0 = out + 2560000;     // [10000][512]
    float* mid1 = out + 7680000;     // [10000][512]
    float* mid2 = out + 12800000;    // [10000][256]

    k_zero   <<<40, 256, 0, stream>>>(deg, zp);
    k_degree <<<1250, 256, 0, stream>>>(e_dst, deg);
    k_scan   <<<1, 256, 0, stream>>>(deg, row_ptr, cursor);
    k_scatter<<<1250, 256, 0, stream>>>(e_src, e_dst, cursor, srcs);

    CvtArgs ca;
    ca.s[0]=ws0; ca.s[1]=wn0; ca.s[2]=wr0;
    ca.s[3]=ws1; ca.s[4]=wn1; ca.s[5]=wr1;
    ca.s[6]=ws2; ca.s[7]=wn2; ca.s[8]=wr2;
    ca.d[0]=wbf0s; ca.d[1]=wbf0n; ca.d[2]=wbf0r;
    ca.d[3]=wbf1s; ca.d[4]=wbf1n; ca.d[5]=wbf1r;
    ca.d[6]=wbf2s; ca.d[7]=wbf2n; ca.d[8]=wbf2r;
    for (int i = 0; i < 6; ++i) ca.n[i] = 262144;
    for (int i = 6; i < 9; ++i) ca.n[i] = 131072;
    k_cvt<<<dim3(128, 9), 256, 0, stream>>>(ca);

    k_pe<<<dim3(157, 8), 256, 0, stream>>>(w_pe, b_pe, h0);

    // grid: 8 xcd-residues * NT n-tiles * 8 m-groups (BM=160: 63 m-tiles + guard)
    k_agg<<<dim3(2500, 2), 256, 0, stream>>>(h0, row_ptr, srcs, aggb, dummy_h0);
    k_layer<512, true,  false, true ><<<dim3(512), 256, 0, stream>>>(
        h0, aggb, wbf0s, wbf0n, wbf0r, b0, rb0, mid0, nullptr, hb);

    k_agg<<<dim3(2500, 2), 256, 0, stream>>>(hb, row_ptr, srcs, aggb, dummy_hb);
    k_layer<512, true,  false, true ><<<dim3(512), 256, 0, stream>>>(
        hb, aggb, wbf1s, wbf1n, wbf1r, b1, rb1, mid1, nullptr, h0);

    k_agg<<<dim3(2500, 2), 256, 0, stream>>>(h0, row_ptr, srcs, aggb, dummy_h0);
    k_layer<256, false, true,  false><<<dim3(256), 256, 0, stream>>>(
        h0, aggb, wbf2s, wbf2n, wbf2r, b2, rb2, mid2, fin, nullptr);
}

// Round 11
// 229.608 us; speedup vs baseline: 1.0655x; 1.0655x over previous
//
#include <hip/hip_runtime.h>

#define N_NODES 10000
#define N_EDGES 320000
#define DIN 512
#define DHID 512
#define DOUT 256

typedef __bf16 bf16x8 __attribute__((ext_vector_type(8)));
typedef float f32x4 __attribute__((ext_vector_type(4)));
typedef unsigned short ushort_t;
typedef unsigned int uint_t;

__device__ __forceinline__ float b2f(ushort_t u){
    union { uint_t i; float f; } v; v.i = (uint_t)u << 16; return v.f;
}
__device__ __forceinline__ float blo(uint_t v){
    union { uint_t i; float f; } u; u.i = v << 16; return u.f;
}
__device__ __forceinline__ float bhi(uint_t v){
    union { uint_t i; float f; } u; u.i = v & 0xffff0000u; return u.f;
}
__device__ __forceinline__ ushort_t f2b(float f){
    union { float f; uint_t i; } v; v.f = f;
    uint_t i = v.i;
    return (ushort_t)((i + 0x7fffu + ((i >> 16) & 1u)) >> 16); // RNE
}

__device__ __forceinline__ void gll16(const ushort_t* g, ushort_t* l){
    __builtin_amdgcn_global_load_lds(
        (const __attribute__((address_space(1))) unsigned int*)g,
        (__attribute__((address_space(3))) unsigned int*)l,
        16, 0, 0);
}

// ---------------- CSR build ----------------

// zero degree array + the 1KB zero-row page used for edge padding
__global__ void k_zero(int* __restrict__ deg, uint_t* __restrict__ zp){
    int i = blockIdx.x * 256 + threadIdx.x;
    if (i < N_NODES) deg[i] = 0;
    if (i < 256) zp[i] = 0u;
}

__global__ void k_degree(const int* __restrict__ dst, int* __restrict__ deg){
    int e = blockIdx.x * 256 + threadIdx.x;
    if (e < N_EDGES) atomicAdd(&deg[dst[e]], 1);
}

// 256 threads, 40 elems/thread serial scan in regs + 8-round block scan.
__global__ void k_scan(const int* __restrict__ deg, int* __restrict__ row_ptr,
                       int* __restrict__ cursor){
    __shared__ int part[256];
    int t = threadIdx.x;
    int base = t * 40;
    int loc[40];
    int s = 0;
    #pragma unroll
    for (int i = 0; i < 40; ++i){
        int idx = base + i;
        int v = (idx < N_NODES) ? deg[idx] : 0;
        s += v; loc[i] = s;          // thread-local inclusive
    }
    part[t] = s;
    __syncthreads();
    int val = s;
    for (int off = 1; off < 256; off <<= 1){
        int x = (t >= off) ? part[t - off] : 0;
        __syncthreads();
        val += x; part[t] = val;
        __syncthreads();
    }
    int exc = val - s;               // exclusive prefix of this thread's chunk
    if (t == 0) row_ptr[0] = 0;
    int run = exc;
    #pragma unroll
    for (int i = 0; i < 40; ++i){
        int idx = base + i;
        if (idx < N_NODES){
            row_ptr[idx + 1] = exc + loc[i];
            cursor[idx] = run;       // bucket start (exclusive)
        }
        run = exc + loc[i];
    }
}

__global__ void k_scatter(const int* __restrict__ src, const int* __restrict__ dst,
                          int* __restrict__ cursor, int* __restrict__ srcs){
    int e = blockIdx.x * 256 + threadIdx.x;
    if (e < N_EDGES){
        int p = atomicAdd(&cursor[dst[e]], 1);
        srcs[p] = src[e];
    }
}

// ---------------- weight f32 -> bf16 conversion (once per call) ----------------

struct CvtArgs { const float* s[9]; ushort_t* d[9]; int n[9]; };

__global__ void k_cvt(CvtArgs a){
    int m = blockIdx.y;
    int i = (blockIdx.x * 256 + threadIdx.x) * 8;
    if (i < a.n[m]){
        const float* sp = a.s[m] + i;
        float4 f0 = *(const float4*)sp;
        float4 f1 = *(const float4*)(sp + 4);
        uint4 u;
        u.x = (uint_t)f2b(f0.x) | ((uint_t)f2b(f0.y) << 16);
        u.y = (uint_t)f2b(f0.z) | ((uint_t)f2b(f0.w) << 16);
        u.z = (uint_t)f2b(f1.x) | ((uint_t)f2b(f1.y) << 16);
        u.w = (uint_t)f2b(f1.z) | ((uint_t)f2b(f1.w) << 16);
        *(uint4*)&a.d[m][i] = u;
    }
}

// ---------------- pe = w_pe^T + b_pe (LDS tile transpose, f32 -> bf16) ----------------

__global__ void k_pe(const float* __restrict__ w_pe, const float* __restrict__ b_pe,
                     ushort_t* __restrict__ h0){
    __shared__ float lt[64][68];  // [n_local][i_local], padded
    int t = threadIdx.x;
    int n0 = blockIdx.x * 64, i0 = blockIdx.y * 64;
    int nc = (t & 15) * 4, ir = t >> 4;   // ir 0..15
    #pragma unroll
    for (int p = 0; p < 4; ++p){
        int i_loc = ir + p * 16;
        float4 v = {0.f, 0.f, 0.f, 0.f};
        if (n0 + nc < N_NODES)
            v = *(const float4*)&w_pe[(size_t)(i0 + i_loc) * N_NODES + n0 + nc];
        lt[nc + 0][i_loc] = v.x;
        lt[nc + 1][i_loc] = v.y;
        lt[nc + 2][i_loc] = v.z;
        lt[nc + 3][i_loc] = v.w;
    }
    __syncthreads();
    int ic = t & 7, nr = t >> 3;   // nr 0..31
    #pragma unroll
    for (int p = 0; p < 2; ++p){
        int n_loc = nr + p * 32;
        int n = n0 + n_loc;
        if (n < N_NODES){
            uint4 u;
            uint_t w01 = (uint_t)f2b(lt[n_loc][ic*8+0] + b_pe[i0+ic*8+0])
                       | ((uint_t)f2b(lt[n_loc][ic*8+1] + b_pe[i0+ic*8+1]) << 16);
            uint_t w23 = (uint_t)f2b(lt[n_loc][ic*8+2] + b_pe[i0+ic*8+2])
                       | ((uint_t)f2b(lt[n_loc][ic*8+3] + b_pe[i0+ic*8+3]) << 16);
            uint_t w45 = (uint_t)f2b(lt[n_loc][ic*8+4] + b_pe[i0+ic*8+4])
                       | ((uint_t)f2b(lt[n_loc][ic*8+5] + b_pe[i0+ic*8+5]) << 16);
            uint_t w67 = (uint_t)f2b(lt[n_loc][ic*8+6] + b_pe[i0+ic*8+6])
                       | ((uint_t)f2b(lt[n_loc][ic*8+7] + b_pe[i0+ic*8+7]) << 16);
            u.x = w01; u.y = w23; u.z = w45; u.w = w67;
            *(uint4*)&h0[(size_t)n * DIN + i0 + ic * 8] = u;
        }
    }
}

// ---------------- mean aggregation v4: readlane index broadcast (reverted) ------
// grid (2500, 4): blockIdx.y = 128-dim panel (2.56MB < 4MB per-XCD L2).
// wave = one node; lane covers 2 dims (4B). Indices bulk-loaded 64-at-a-time into
// lanes, extracted per-edge with v_readlane (pure VALU, no index-fetch latency).
// Ragged tail padded with `dummy` = index of a zeroed 1KB row (exact, adds 0).

#define AGG_EDGE(e, CH) { \
    int s_ = __builtin_amdgcn_readlane(sr, (e)); \
    uint_t v_ = *(const uint_t*)&X[((size_t)(uint_t)s_ << 9) + col]; \
    CH##0 += blo(v_); CH##1 += bhi(v_); }

__global__ __launch_bounds__(256) void k_agg(
    const ushort_t* __restrict__ X, const int* __restrict__ row_ptr,
    const int* __restrict__ srcs, ushort_t* __restrict__ out, int dummy)
{
    int w = threadIdx.x >> 6, lane = threadIdx.x & 63;
    int n = blockIdx.x * 4 + w;
    int col = blockIdx.y * 128 + lane * 2;
    int beg = row_ptr[n], end = row_ptr[n + 1];
    int deg = end - beg;
    float a0=0.f,a1=0.f, p0=0.f,p1=0.f, c0=0.f,c1=0.f, d0=0.f,d1=0.f;

    for (int base = beg; base < end; base += 128){
        int rem = end - base;
        int i0 = (lane < rem)      ? srcs[base + lane]      : dummy;
        int i1 = (lane + 64 < rem) ? srcs[base + lane + 64] : dummy;
        int cnt = rem < 128 ? rem : 128;
        #pragma unroll
        for (int k = 0; k < 8; ++k){
            if (k * 16 < cnt){
                int sr = (k < 4) ? i0 : i1;
                int L = (k & 3) * 16;
                AGG_EDGE(L + 0,  a) AGG_EDGE(L + 1,  p) AGG_EDGE(L + 2,  c) AGG_EDGE(L + 3,  d)
                AGG_EDGE(L + 4,  a) AGG_EDGE(L + 5,  p) AGG_EDGE(L + 6,  c) AGG_EDGE(L + 7,  d)
                AGG_EDGE(L + 8,  a) AGG_EDGE(L + 9,  p) AGG_EDGE(L + 10, c) AGG_EDGE(L + 11, d)
                AGG_EDGE(L + 12, a) AGG_EDGE(L + 13, p) AGG_EDGE(L + 14, c) AGG_EDGE(L + 15, d)
            }
        }
    }

    float r0 = (a0 + p0) + (c0 + d0);
    float r1 = (a1 + p1) + (c1 + d1);
    float inv = (deg > 0) ? 1.f / (float)deg : 1.f;
    uint_t o = (uint_t)f2b(r0 * inv) | ((uint_t)f2b(r1 * inv) << 16);
    *(uint_t*)&out[(size_t)n * 512 + col] = o;
}

// ---------------- fused SAGE layer: one-batch BM=160, template BN ----------------
// BM=160, BK=32; 4 waves (2x2), wave tile 80 x BN/2; double-buffered LDS,
// 2 blocks/CU; one co-resident batch. Blocks sharing an m-tile land on the
// same XCD (bid%8 = m%8). BN=64 for DHID layers (504 jobs), BN=32 for the
// DOUT layer (504 jobs instead of 252 -> full chip).
// Y(f32) = [leaky?](X@Ws^T + Agg@Wn^T + b) + X@Wr^T + rb

template<int DO, int BN, bool ACT, bool DUAL2, bool WRITE_BF>
__global__ __launch_bounds__(256, 2) void k_layer(
    const ushort_t* __restrict__ X, const ushort_t* __restrict__ G,
    const ushort_t* __restrict__ Ws, const ushort_t* __restrict__ Wn,
    const ushort_t* __restrict__ Wr,
    const float* __restrict__ b, const float* __restrict__ rb,
    float* __restrict__ Y, float* __restrict__ Y2, ushort_t* __restrict__ YB)
{
    constexpr int BM   = 160;
    constexpr int NT   = DO / BN;          // n-tiles
    constexpr int WTN  = BN / 32;          // n-MFMA blocks per wave (2 or 1)
    constexpr int NCH  = (2 * BM + 3 * BN) / 16;   // 1KB staging chunks (32 or 26)
    constexpr int CHPW = (NCH + 3) / 4;            // chunks per wave (8 or 7)
    constexpr int OG   = BM * 32;                  // ushort offsets
    constexpr int OS   = 2 * BM * 32;
    constexpr int WS32 = BN * 32;
    constexpr int BUFSZ = OS + 3 * WS32;
    __shared__ __align__(16) ushort_t smem[2][BUFSZ];

    int t = threadIdx.x;
    int bid = blockIdx.x;
    int r8 = bid & 7, q8 = bid >> 3;
    int m_t = (q8 / NT) * 8 + r8;
    int n_t = q8 % NT;
    if (m_t * BM >= N_NODES) return;   // uniform whole-block guard
    int m0 = m_t * BM, n0 = n_t * BN;

    int lane = t & 63, w = t >> 6;
    int wr = w >> 1, wc = w & 1;        // wave tile: rows wr*80, cols wc*(BN/2)

    // staging: NCH chunks of 1KB (16 rows x 64B), CHPW per wave (guarded)
    const ushort_t* gptr[CHPW];
    int coff[CHPW];
    bool gv[CHPW];
    int rl = lane >> 2, sl = (lane & 3) * 8;
    #pragma unroll
    for (int i = 0; i < CHPW; ++i){
        int qq = w * CHPW + i;
        gv[i] = (qq < NCH);
        int qc = gv[i] ? qq : 0;
        const ushort_t* gA; int rowbase, off;
        if (qc < 10)      { gA = X;  rowbase = m0 + qc * 16;        off = qc * 512; }
        else if (qc < 20) { gA = G;  rowbase = m0 + (qc - 10) * 16; off = OG + (qc - 10) * 512; }
        else {
            int q2 = qc - 20;
            int sec = q2 / (BN / 16), wi = q2 % (BN / 16);
            gA = (sec == 0) ? Ws : (sec == 1) ? Wn : Wr;
            rowbase = n0 + wi * 16;
            off = OS + sec * WS32 + wi * 512;
        }
        gptr[i] = gA + (size_t)(rowbase + rl) * 512 + sl;
        coff[i] = off;   // wave-uniform; HW writes base + lane*16B
    }

    f32x4 accS[5][WTN] = {}, accG[5][WTN] = {}, accR[5][WTN] = {};
    int r16 = lane & 15;
    int arow = wr * 80 + r16;
    int brow = wc * (BN / 2) + r16;
    int kk = (lane >> 4) * 8;

    // prologue: stage K-step 0 into buffer 0
    #pragma unroll
    for (int i = 0; i < CHPW; ++i) if (gv[i]) gll16(gptr[i], &smem[0][coff[i]]);
    __syncthreads();

    int cur = 0;
    for (int ks = 0; ks < 16; ++ks){
        if (ks < 15){
            int k0 = (ks + 1) * 32;
            #pragma unroll
            for (int i = 0; i < CHPW; ++i) if (gv[i]) gll16(gptr[i] + k0, &smem[cur ^ 1][coff[i]]);
        }

        const ushort_t* sb = smem[cur];
        bf16x8 ax[5], ag[5], bs[WTN], bn_[WTN], brr[WTN];
        #pragma unroll
        for (int m = 0; m < 5; ++m){
            ax[m] = *(const bf16x8*)&sb[(arow + m * 16) * 32 + kk];
            ag[m] = *(const bf16x8*)&sb[OG + (arow + m * 16) * 32 + kk];
        }
        #pragma unroll
        for (int n = 0; n < WTN; ++n){
            bs[n]  = *(const bf16x8*)&sb[OS            + (brow + n * 16) * 32 + kk];
            bn_[n] = *(const bf16x8*)&sb[OS + WS32     + (brow + n * 16) * 32 + kk];
            brr[n] = *(const bf16x8*)&sb[OS + 2 * WS32 + (brow + n * 16) * 32 + kk];
        }
        #pragma unroll
        for (int m = 0; m < 5; ++m)
            #pragma unroll
            for (int n = 0; n < WTN; ++n){
                accS[m][n] = __builtin_amdgcn_mfma_f32_16x16x32_bf16(ax[m], bs[n],  accS[m][n], 0, 0, 0);
                accG[m][n] = __builtin_amdgcn_mfma_f32_16x16x32_bf16(ag[m], bn_[n], accG[m][n], 0, 0, 0);
                accR[m][n] = __builtin_amdgcn_mfma_f32_16x16x32_bf16(ax[m], brr[n], accR[m][n], 0, 0, 0);
            }

        __syncthreads();   // next buffer staged; all waves done reading cur
        cur ^= 1;
    }

    // epilogue: C/D layout col = lane&15, row = (lane>>4)*4 + reg
    int col_l = lane & 15;
    int row_l = (lane >> 4) * 4;
    #pragma unroll
    for (int n = 0; n < WTN; ++n){
        int col = n0 + wc * (BN / 2) + n * 16 + col_l;
        float bb = b[col], rbb = rb[col];
        #pragma unroll
        for (int m = 0; m < 5; ++m){
            #pragma unroll
            for (int j = 0; j < 4; ++j){
                int row = m0 + wr * 80 + m * 16 + row_l + j;
                if (row < N_NODES){
                    float v = accS[m][n][j] + accG[m][n][j] + bb;
                    if (ACT) v = (v > 0.f) ? v : 0.01f * v;
                    v += accR[m][n][j] + rbb;
                    Y[(size_t)row * DO + col] = v;
                    if (DUAL2) Y2[(size_t)row * DO + col] = v;
                    if (WRITE_BF) YB[(size_t)row * DO + col] = f2b(v);
                }
            }
        }
    }
}

// ---------------- launch ----------------

extern "C" void kernel_launch(void* const* d_in, const int* in_sizes, int n_in,
                              void* d_out, int out_size, void* d_ws, size_t ws_size,
                              hipStream_t stream) {
    const int* edge  = (const int*)d_in[0];
    const int* e_src = edge;
    const int* e_dst = edge + N_EDGES;
    const float* w_pe = (const float*)d_in[1];
    const float* b_pe = (const float*)d_in[2];
    const float* ws0 = (const float*)d_in[3];
    const float* wn0 = (const float*)d_in[4];
    const float* b0  = (const float*)d_in[5];
    const float* wr0 = (const float*)d_in[6];
    const float* rb0 = (const float*)d_in[7];
    const float* ws1 = (const float*)d_in[8];
    const float* wn1 = (const float*)d_in[9];
    const float* b1  = (const float*)d_in[10];
    const float* wr1 = (const float*)d_in[11];
    const float* rb1 = (const float*)d_in[12];
    const float* ws2 = (const float*)d_in[13];
    const float* wn2 = (const float*)d_in[14];
    const float* b2  = (const float*)d_in[15];
    const float* wr2 = (const float*)d_in[16];
    const float* rb2 = (const float*)d_in[17];

    char* wsb = (char*)d_ws;
    ushort_t* h0   = (ushort_t*)wsb;                       // 10,240,000 B @ 0
    ushort_t* hb   = (ushort_t*)(wsb + 10240000);          // 10,240,000 B
    ushort_t* aggb = (ushort_t*)(wsb + 20480000);          // 10,240,000 B
    ushort_t* wbf  = (ushort_t*)(wsb + 30720000);          // 3,932,160 B
    int* deg     = (int*)(wsb + 34652160);                 // 10016 ints
    int* row_ptr = deg + 10016;
    int* cursor  = row_ptr + 10016;
    int* srcs    = cursor + 10016;                         // 320000 ints -> ends 36,052,352
    uint_t* zp   = (uint_t*)(wsb + 36052992);              // 1KB zero row (1024-aligned)
    // dummy row indices: (zp_off - buf_off) / 1024
    const int dummy_h0 = 35208;   // (36052992 - 0) / 1024
    const int dummy_hb = 25208;   // (36052992 - 10240000) / 1024

    ushort_t* wbf0s = wbf;
    ushort_t* wbf0n = wbf + 262144;
    ushort_t* wbf0r = wbf + 524288;
    ushort_t* wbf1s = wbf + 786432;
    ushort_t* wbf1n = wbf + 1048576;
    ushort_t* wbf1r = wbf + 1310720;
    ushort_t* wbf2s = wbf + 1572864;
    ushort_t* wbf2n = wbf + 1703936;
    ushort_t* wbf2r = wbf + 1835008;

    float* out  = (float*)d_out;
    float* fin  = out;               // [10000][256]
    float* mid0 = out + 2560000;     // [10000][512]
    float* mid1 = out + 7680000;     // [10000][512]
    float* mid2 = out + 12800000;    // [10000][256]

    k_zero   <<<40, 256, 0, stream>>>(deg, zp);
    k_degree <<<1250, 256, 0, stream>>>(e_dst, deg);
    k_scan   <<<1, 256, 0, stream>>>(deg, row_ptr, cursor);
    k_scatter<<<1250, 256, 0, stream>>>(e_src, e_dst, cursor, srcs);

    CvtArgs ca;
    ca.s[0]=ws0; ca.s[1]=wn0; ca.s[2]=wr0;
    ca.s[3]=ws1; ca.s[4]=wn1; ca.s[5]=wr1;
    ca.s[6]=ws2; ca.s[7]=wn2; ca.s[8]=wr2;
    ca.d[0]=wbf0s; ca.d[1]=wbf0n; ca.d[2]=wbf0r;
    ca.d[3]=wbf1s; ca.d[4]=wbf1n; ca.d[5]=wbf1r;
    ca.d[6]=wbf2s; ca.d[7]=wbf2n; ca.d[8]=wbf2r;
    for (int i = 0; i < 6; ++i) ca.n[i] = 262144;
    for (int i = 6; i < 9; ++i) ca.n[i] = 131072;
    k_cvt<<<dim3(128, 9), 256, 0, stream>>>(ca);

    k_pe<<<dim3(157, 8), 256, 0, stream>>>(w_pe, b_pe, h0);

    // grid: 8 xcd-residues * NT n-tiles * 8 m-groups (BM=160: 63 m-tiles + guard)
    k_agg<<<dim3(2500, 4), 256, 0, stream>>>(h0, row_ptr, srcs, aggb, dummy_h0);
    k_layer<512, 64, true,  false, true ><<<dim3(512), 256, 0, stream>>>(
        h0, aggb, wbf0s, wbf0n, wbf0r, b0, rb0, mid0, nullptr, hb);

    k_agg<<<dim3(2500, 4), 256, 0, stream>>>(hb, row_ptr, srcs, aggb, dummy_hb);
    k_layer<512, 64, true,  false, true ><<<dim3(512), 256, 0, stream>>>(
        hb, aggb, wbf1s, wbf1n, wbf1r, b1, rb1, mid1, nullptr, h0);

    k_agg<<<dim3(2500, 4), 256, 0, stream>>>(h0, row_ptr, srcs, aggb, dummy_h0);
    k_layer<256, 32, false, true,  false><<<dim3(512), 256, 0, stream>>>(
        h0, aggb, wbf2s, wbf2n, wbf2r, b2, rb2, mid2, fin, nullptr);
}

// Round 12
// 228.762 us; speedup vs baseline: 1.0695x; 1.0037x over previous
//
#include <hip/hip_runtime.h>

#define N_NODES 10000
#define N_EDGES 320000
#define DIN 512
#define DHID 512
#define DOUT 256

typedef __bf16 bf16x8 __attribute__((ext_vector_type(8)));
typedef float f32x4 __attribute__((ext_vector_type(4)));
typedef unsigned short ushort_t;
typedef unsigned int uint_t;

__device__ __forceinline__ float b2f(ushort_t u){
    union { uint_t i; float f; } v; v.i = (uint_t)u << 16; return v.f;
}
__device__ __forceinline__ float blo(uint_t v){
    union { uint_t i; float f; } u; u.i = v << 16; return u.f;
}
__device__ __forceinline__ float bhi(uint_t v){
    union { uint_t i; float f; } u; u.i = v & 0xffff0000u; return u.f;
}
__device__ __forceinline__ ushort_t f2b(float f){
    union { float f; uint_t i; } v; v.f = f;
    uint_t i = v.i;
    return (ushort_t)((i + 0x7fffu + ((i >> 16) & 1u)) >> 16); // RNE
}

__device__ __forceinline__ void gll16(const ushort_t* g, ushort_t* l){
    __builtin_amdgcn_global_load_lds(
        (const __attribute__((address_space(1))) unsigned int*)g,
        (__attribute__((address_space(3))) unsigned int*)l,
        16, 0, 0);
}

// ---------------- CSR build ----------------

// zero degree array + the 1KB zero-row page used for edge padding
__global__ void k_zero(int* __restrict__ deg, uint_t* __restrict__ zp){
    int i = blockIdx.x * 256 + threadIdx.x;
    if (i < N_NODES) deg[i] = 0;
    if (i < 256) zp[i] = 0u;
}

__global__ void k_degree(const int* __restrict__ dst, int* __restrict__ deg){
    int e = blockIdx.x * 256 + threadIdx.x;
    if (e < N_EDGES) atomicAdd(&deg[dst[e]], 1);
}

// 256 threads, 40 elems/thread serial scan in regs + 8-round block scan.
__global__ void k_scan(const int* __restrict__ deg, int* __restrict__ row_ptr,
                       int* __restrict__ cursor){
    __shared__ int part[256];
    int t = threadIdx.x;
    int base = t * 40;
    int loc[40];
    int s = 0;
    #pragma unroll
    for (int i = 0; i < 40; ++i){
        int idx = base + i;
        int v = (idx < N_NODES) ? deg[idx] : 0;
        s += v; loc[i] = s;          // thread-local inclusive
    }
    part[t] = s;
    __syncthreads();
    int val = s;
    for (int off = 1; off < 256; off <<= 1){
        int x = (t >= off) ? part[t - off] : 0;
        __syncthreads();
        val += x; part[t] = val;
        __syncthreads();
    }
    int exc = val - s;               // exclusive prefix of this thread's chunk
    if (t == 0) row_ptr[0] = 0;
    int run = exc;
    #pragma unroll
    for (int i = 0; i < 40; ++i){
        int idx = base + i;
        if (idx < N_NODES){
            row_ptr[idx + 1] = exc + loc[i];
            cursor[idx] = run;       // bucket start (exclusive)
        }
        run = exc + loc[i];
    }
}

__global__ void k_scatter(const int* __restrict__ src, const int* __restrict__ dst,
                          int* __restrict__ cursor, int* __restrict__ srcs){
    int e = blockIdx.x * 256 + threadIdx.x;
    if (e < N_EDGES){
        int p = atomicAdd(&cursor[dst[e]], 1);
        srcs[p] = src[e];
    }
}

// ---------------- weight f32 -> bf16 conversion (once per call) ----------------

struct CvtArgs { const float* s[9]; ushort_t* d[9]; int n[9]; };

__global__ void k_cvt(CvtArgs a){
    int m = blockIdx.y;
    int i = (blockIdx.x * 256 + threadIdx.x) * 8;
    if (i < a.n[m]){
        const float* sp = a.s[m] + i;
        float4 f0 = *(const float4*)sp;
        float4 f1 = *(const float4*)(sp + 4);
        uint4 u;
        u.x = (uint_t)f2b(f0.x) | ((uint_t)f2b(f0.y) << 16);
        u.y = (uint_t)f2b(f0.z) | ((uint_t)f2b(f0.w) << 16);
        u.z = (uint_t)f2b(f1.x) | ((uint_t)f2b(f1.y) << 16);
        u.w = (uint_t)f2b(f1.z) | ((uint_t)f2b(f1.w) << 16);
        *(uint4*)&a.d[m][i] = u;
    }
}

// ---------------- pe = w_pe^T + b_pe (LDS tile transpose, f32 -> bf16) ----------------

__global__ void k_pe(const float* __restrict__ w_pe, const float* __restrict__ b_pe,
                     ushort_t* __restrict__ h0){
    __shared__ float lt[64][68];  // [n_local][i_local], padded
    int t = threadIdx.x;
    int n0 = blockIdx.x * 64, i0 = blockIdx.y * 64;
    int nc = (t & 15) * 4, ir = t >> 4;   // ir 0..15
    #pragma unroll
    for (int p = 0; p < 4; ++p){
        int i_loc = ir + p * 16;
        float4 v = {0.f, 0.f, 0.f, 0.f};
        if (n0 + nc < N_NODES)
            v = *(const float4*)&w_pe[(size_t)(i0 + i_loc) * N_NODES + n0 + nc];
        lt[nc + 0][i_loc] = v.x;
        lt[nc + 1][i_loc] = v.y;
        lt[nc + 2][i_loc] = v.z;
        lt[nc + 3][i_loc] = v.w;
    }
    __syncthreads();
    int ic = t & 7, nr = t >> 3;   // nr 0..31
    #pragma unroll
    for (int p = 0; p < 2; ++p){
        int n_loc = nr + p * 32;
        int n = n0 + n_loc;
        if (n < N_NODES){
            uint4 u;
            uint_t w01 = (uint_t)f2b(lt[n_loc][ic*8+0] + b_pe[i0+ic*8+0])
                       | ((uint_t)f2b(lt[n_loc][ic*8+1] + b_pe[i0+ic*8+1]) << 16);
            uint_t w23 = (uint_t)f2b(lt[n_loc][ic*8+2] + b_pe[i0+ic*8+2])
                       | ((uint_t)f2b(lt[n_loc][ic*8+3] + b_pe[i0+ic*8+3]) << 16);
            uint_t w45 = (uint_t)f2b(lt[n_loc][ic*8+4] + b_pe[i0+ic*8+4])
                       | ((uint_t)f2b(lt[n_loc][ic*8+5] + b_pe[i0+ic*8+5]) << 16);
            uint_t w67 = (uint_t)f2b(lt[n_loc][ic*8+6] + b_pe[i0+ic*8+6])
                       | ((uint_t)f2b(lt[n_loc][ic*8+7] + b_pe[i0+ic*8+7]) << 16);
            u.x = w01; u.y = w23; u.z = w45; u.w = w67;
            *(uint4*)&h0[(size_t)n * DIN + i0 + ic * 8] = u;
        }
    }
}

// ---------------- mean aggregation v6: readlane, 64-edge superblock ------------
// grid (2500, 4): blockIdx.y = 128-dim panel (2.56MB < 4MB per-XCD L2).
// wave = one node; lane covers 2 dims (4B). ONE 256B index load per superblock
// (deg~Poisson(32): one superblock for ~all nodes), per-edge index extracted with
// v_readlane (pure VALU). Ragged tail padded with `dummy` -> zeroed row (exact).

#define AGG_EDGE(e, CH) { \
    int s_ = __builtin_amdgcn_readlane(sr, (e)); \
    uint_t v_ = *(const uint_t*)&X[((size_t)(uint_t)s_ << 9) + col]; \
    CH##0 += blo(v_); CH##1 += bhi(v_); }

__global__ __launch_bounds__(256) void k_agg(
    const ushort_t* __restrict__ X, const int* __restrict__ row_ptr,
    const int* __restrict__ srcs, ushort_t* __restrict__ out, int dummy)
{
    int w = threadIdx.x >> 6, lane = threadIdx.x & 63;
    int n = blockIdx.x * 4 + w;
    int col = blockIdx.y * 128 + lane * 2;
    int beg = row_ptr[n], end = row_ptr[n + 1];
    int deg = end - beg;
    float a0=0.f,a1=0.f, p0=0.f,p1=0.f, c0=0.f,c1=0.f, d0=0.f,d1=0.f;

    for (int base = beg; base < end; base += 64){
        int rem = end - base;
        int sr = (lane < rem) ? srcs[base + lane] : dummy;
        int cnt = rem < 64 ? rem : 64;
        #pragma unroll
        for (int k = 0; k < 4; ++k){
            if (k * 16 < cnt){
                int L = k * 16;
                AGG_EDGE(L + 0,  a) AGG_EDGE(L + 1,  p) AGG_EDGE(L + 2,  c) AGG_EDGE(L + 3,  d)
                AGG_EDGE(L + 4,  a) AGG_EDGE(L + 5,  p) AGG_EDGE(L + 6,  c) AGG_EDGE(L + 7,  d)
                AGG_EDGE(L + 8,  a) AGG_EDGE(L + 9,  p) AGG_EDGE(L + 10, c) AGG_EDGE(L + 11, d)
                AGG_EDGE(L + 12, a) AGG_EDGE(L + 13, p) AGG_EDGE(L + 14, c) AGG_EDGE(L + 15, d)
            }
        }
    }

    float r0 = (a0 + p0) + (c0 + d0);
    float r1 = (a1 + p1) + (c1 + d1);
    float inv = (deg > 0) ? 1.f / (float)deg : 1.f;
    uint_t o = (uint_t)f2b(r0 * inv) | ((uint_t)f2b(r1 * inv) << 16);
    *(uint_t*)&out[(size_t)n * 512 + col] = o;
}

// ---------------- fused SAGE layer: one-batch BM=160, template BN ----------------
// BM=160, BK=32; 4 waves (2x2), wave tile 80 x BN/2; double-buffered LDS,
// 2 blocks/CU; one co-resident batch. Blocks sharing an m-tile land on the
// same XCD (bid%8 = m%8). BN=64 for DHID layers (504 jobs), BN=32 for the
// DOUT layer (504 jobs -> full chip).
// Y(f32) = [leaky?](X@Ws^T + Agg@Wn^T + b) + X@Wr^T + rb

template<int DO, int BN, bool ACT, bool DUAL2, bool WRITE_BF>
__global__ __launch_bounds__(256, 2) void k_layer(
    const ushort_t* __restrict__ X, const ushort_t* __restrict__ G,
    const ushort_t* __restrict__ Ws, const ushort_t* __restrict__ Wn,
    const ushort_t* __restrict__ Wr,
    const float* __restrict__ b, const float* __restrict__ rb,
    float* __restrict__ Y, float* __restrict__ Y2, ushort_t* __restrict__ YB)
{
    constexpr int BM   = 160;
    constexpr int NT   = DO / BN;          // n-tiles
    constexpr int WTN  = BN / 32;          // n-MFMA blocks per wave (2 or 1)
    constexpr int NCH  = (2 * BM + 3 * BN) / 16;   // 1KB staging chunks (32 or 26)
    constexpr int CHPW = (NCH + 3) / 4;            // chunks per wave (8 or 7)
    constexpr int OG   = BM * 32;                  // ushort offsets
    constexpr int OS   = 2 * BM * 32;
    constexpr int WS32 = BN * 32;
    constexpr int BUFSZ = OS + 3 * WS32;
    __shared__ __align__(16) ushort_t smem[2][BUFSZ];

    int t = threadIdx.x;
    int bid = blockIdx.x;
    int r8 = bid & 7, q8 = bid >> 3;
    int m_t = (q8 / NT) * 8 + r8;
    int n_t = q8 % NT;
    if (m_t * BM >= N_NODES) return;   // uniform whole-block guard
    int m0 = m_t * BM, n0 = n_t * BN;

    int lane = t & 63, w = t >> 6;
    int wr = w >> 1, wc = w & 1;        // wave tile: rows wr*80, cols wc*(BN/2)

    // staging: NCH chunks of 1KB (16 rows x 64B), CHPW per wave (guarded)
    const ushort_t* gptr[CHPW];
    int coff[CHPW];
    bool gv[CHPW];
    int rl = lane >> 2, sl = (lane & 3) * 8;
    #pragma unroll
    for (int i = 0; i < CHPW; ++i){
        int qq = w * CHPW + i;
        gv[i] = (qq < NCH);
        int qc = gv[i] ? qq : 0;
        const ushort_t* gA; int rowbase, off;
        if (qc < 10)      { gA = X;  rowbase = m0 + qc * 16;        off = qc * 512; }
        else if (qc < 20) { gA = G;  rowbase = m0 + (qc - 10) * 16; off = OG + (qc - 10) * 512; }
        else {
            int q2 = qc - 20;
            int sec = q2 / (BN / 16), wi = q2 % (BN / 16);
            gA = (sec == 0) ? Ws : (sec == 1) ? Wn : Wr;
            rowbase = n0 + wi * 16;
            off = OS + sec * WS32 + wi * 512;
        }
        gptr[i] = gA + (size_t)(rowbase + rl) * 512 + sl;
        coff[i] = off;   // wave-uniform; HW writes base + lane*16B
    }

    f32x4 accS[5][WTN] = {}, accG[5][WTN] = {}, accR[5][WTN] = {};
    int r16 = lane & 15;
    int arow = wr * 80 + r16;
    int brow = wc * (BN / 2) + r16;
    int kk = (lane >> 4) * 8;

    // prologue: stage K-step 0 into buffer 0
    #pragma unroll
    for (int i = 0; i < CHPW; ++i) if (gv[i]) gll16(gptr[i], &smem[0][coff[i]]);
    __syncthreads();

    int cur = 0;
    for (int ks = 0; ks < 16; ++ks){
        if (ks < 15){
            int k0 = (ks + 1) * 32;
            #pragma unroll
            for (int i = 0; i < CHPW; ++i) if (gv[i]) gll16(gptr[i] + k0, &smem[cur ^ 1][coff[i]]);
        }

        const ushort_t* sb = smem[cur];
        bf16x8 ax[5], ag[5], bs[WTN], bn_[WTN], brr[WTN];
        #pragma unroll
        for (int m = 0; m < 5; ++m){
            ax[m] = *(const bf16x8*)&sb[(arow + m * 16) * 32 + kk];
            ag[m] = *(const bf16x8*)&sb[OG + (arow + m * 16) * 32 + kk];
        }
        #pragma unroll
        for (int n = 0; n < WTN; ++n){
            bs[n]  = *(const bf16x8*)&sb[OS            + (brow + n * 16) * 32 + kk];
            bn_[n] = *(const bf16x8*)&sb[OS + WS32     + (brow + n * 16) * 32 + kk];
            brr[n] = *(const bf16x8*)&sb[OS + 2 * WS32 + (brow + n * 16) * 32 + kk];
        }
        #pragma unroll
        for (int m = 0; m < 5; ++m)
            #pragma unroll
            for (int n = 0; n < WTN; ++n){
                accS[m][n] = __builtin_amdgcn_mfma_f32_16x16x32_bf16(ax[m], bs[n],  accS[m][n], 0, 0, 0);
                accG[m][n] = __builtin_amdgcn_mfma_f32_16x16x32_bf16(ag[m], bn_[n], accG[m][n], 0, 0, 0);
                accR[m][n] = __builtin_amdgcn_mfma_f32_16x16x32_bf16(ax[m], brr[n], accR[m][n], 0, 0, 0);
            }

        __syncthreads();   // next buffer staged; all waves done reading cur
        cur ^= 1;
    }

    // epilogue: C/D layout col = lane&15, row = (lane>>4)*4 + reg
    int col_l = lane & 15;
    int row_l = (lane >> 4) * 4;
    #pragma unroll
    for (int n = 0; n < WTN; ++n){
        int col = n0 + wc * (BN / 2) + n * 16 + col_l;
        float bb = b[col], rbb = rb[col];
        #pragma unroll
        for (int m = 0; m < 5; ++m){
            #pragma unroll
            for (int j = 0; j < 4; ++j){
                int row = m0 + wr * 80 + m * 16 + row_l + j;
                if (row < N_NODES){
                    float v = accS[m][n][j] + accG[m][n][j] + bb;
                    if (ACT) v = (v > 0.f) ? v : 0.01f * v;
                    v += accR[m][n][j] + rbb;
                    Y[(size_t)row * DO + col] = v;
                    if (DUAL2) Y2[(size_t)row * DO + col] = v;
                    if (WRITE_BF) YB[(size_t)row * DO + col] = f2b(v);
                }
            }
        }
    }
}

// ---------------- launch ----------------

extern "C" void kernel_launch(void* const* d_in, const int* in_sizes, int n_in,
                              void* d_out, int out_size, void* d_ws, size_t ws_size,
                              hipStream_t stream) {
    const int* edge  = (const int*)d_in[0];
    const int* e_src = edge;
    const int* e_dst = edge + N_EDGES;
    const float* w_pe = (const float*)d_in[1];
    const float* b_pe = (const float*)d_in[2];
    const float* ws0 = (const float*)d_in[3];
    const float* wn0 = (const float*)d_in[4];
    const float* b0  = (const float*)d_in[5];
    const float* wr0 = (const float*)d_in[6];
    const float* rb0 = (const float*)d_in[7];
    const float* ws1 = (const float*)d_in[8];
    const float* wn1 = (const float*)d_in[9];
    const float* b1  = (const float*)d_in[10];
    const float* wr1 = (const float*)d_in[11];
    const float* rb1 = (const float*)d_in[12];
    const float* ws2 = (const float*)d_in[13];
    const float* wn2 = (const float*)d_in[14];
    const float* b2  = (const float*)d_in[15];
    const float* wr2 = (const float*)d_in[16];
    const float* rb2 = (const float*)d_in[17];

    char* wsb = (char*)d_ws;
    ushort_t* h0   = (ushort_t*)wsb;                       // 10,240,000 B @ 0
    ushort_t* hb   = (ushort_t*)(wsb + 10240000);          // 10,240,000 B
    ushort_t* aggb = (ushort_t*)(wsb + 20480000);          // 10,240,000 B
    ushort_t* wbf  = (ushort_t*)(wsb + 30720000);          // 3,932,160 B
    int* deg     = (int*)(wsb + 34652160);                 // 10016 ints
    int* row_ptr = deg + 10016;
    int* cursor  = row_ptr + 10016;
    int* srcs    = cursor + 10016;                         // 320000 ints -> ends 36,052,352
    uint_t* zp   = (uint_t*)(wsb + 36052992);              // 1KB zero row (1024-aligned)
    // dummy row indices: (zp_off - buf_off) / 1024
    const int dummy_h0 = 35208;   // (36052992 - 0) / 1024
    const int dummy_hb = 25208;   // (36052992 - 10240000) / 1024

    ushort_t* wbf0s = wbf;
    ushort_t* wbf0n = wbf + 262144;
    ushort_t* wbf0r = wbf + 524288;
    ushort_t* wbf1s = wbf + 786432;
    ushort_t* wbf1n = wbf + 1048576;
    ushort_t* wbf1r = wbf + 1310720;
    ushort_t* wbf2s = wbf + 1572864;
    ushort_t* wbf2n = wbf + 1703936;
    ushort_t* wbf2r = wbf + 1835008;

    float* out  = (float*)d_out;
    float* fin  = out;               // [10000][256]
    float* mid0 = out + 2560000;     // [10000][512]
    float* mid1 = out + 7680000;     // [10000][512]
    float* mid2 = out + 12800000;    // [10000][256]

    k_zero   <<<40, 256, 0, stream>>>(deg, zp);
    k_degree <<<1250, 256, 0, stream>>>(e_dst, deg);
    k_scan   <<<1, 256, 0, stream>>>(deg, row_ptr, cursor);
    k_scatter<<<1250, 256, 0, stream>>>(e_src, e_dst, cursor, srcs);

    CvtArgs ca;
    ca.s[0]=ws0; ca.s[1]=wn0; ca.s[2]=wr0;
    ca.s[3]=ws1; ca.s[4]=wn1; ca.s[5]=wr1;
    ca.s[6]=ws2; ca.s[7]=wn2; ca.s[8]=wr2;
    ca.d[0]=wbf0s; ca.d[1]=wbf0n; ca.d[2]=wbf0r;
    ca.d[3]=wbf1s; ca.d[4]=wbf1n; ca.d[5]=wbf1r;
    ca.d[6]=wbf2s; ca.d[7]=wbf2n; ca.d[8]=wbf2r;
    for (int i = 0; i < 6; ++i) ca.n[i] = 262144;
    for (int i = 6; i < 9; ++i) ca.n[i] = 131072;
    k_cvt<<<dim3(128, 9), 256, 0, stream>>>(ca);

    k_pe<<<dim3(157, 8), 256, 0, stream>>>(w_pe, b_pe, h0);

    // grid: 8 xcd-residues * NT n-tiles * 8 m-groups (BM=160: 63 m-tiles + guard)
    k_agg<<<dim3(2500, 4), 256, 0, stream>>>(h0, row_ptr, srcs, aggb, dummy_h0);
    k_layer<512, 64, true,  false, true ><<<dim3(512), 256, 0, stream>>>(
        h0, aggb, wbf0s, wbf0n, wbf0r, b0, rb0, mid0, nullptr, hb);

    k_agg<<<dim3(2500, 4), 256, 0, stream>>>(hb, row_ptr, srcs, aggb, dummy_hb);
    k_layer<512, 64, true,  false, true ><<<dim3(512), 256, 0, stream>>>(
        hb, aggb, wbf1s, wbf1n, wbf1r, b1, rb1, mid1, nullptr, h0);

    k_agg<<<dim3(2500, 4), 256, 0, stream>>>(h0, row_ptr, srcs, aggb, dummy_h0);
    k_layer<256, 32, false, true,  false><<<dim3(512), 256, 0, stream>>>(
        h0, aggb, wbf2s, wbf2n, wbf2r, b2, rb2, mid2, fin, nullptr);
}

// Round 13
// 214.078 us; speedup vs baseline: 1.1428x; 1.0686x over previous
//
#include <hip/hip_runtime.h>

#define N_NODES 10000
#define N_EDGES 320000
#define DIN 512
#define DHID 512
#define DOUT 256

typedef __bf16 bf16x8 __attribute__((ext_vector_type(8)));
typedef float f32x4 __attribute__((ext_vector_type(4)));
typedef unsigned short ushort_t;
typedef unsigned int uint_t;

__device__ __forceinline__ float b2f(ushort_t u){
    union { uint_t i; float f; } v; v.i = (uint_t)u << 16; return v.f;
}
__device__ __forceinline__ float blo(uint_t v){
    union { uint_t i; float f; } u; u.i = v << 16; return u.f;
}
__device__ __forceinline__ float bhi(uint_t v){
    union { uint_t i; float f; } u; u.i = v & 0xffff0000u; return u.f;
}
__device__ __forceinline__ ushort_t f2b(float f){
    union { float f; uint_t i; } v; v.f = f;
    uint_t i = v.i;
    return (ushort_t)((i + 0x7fffu + ((i >> 16) & 1u)) >> 16); // RNE
}

__device__ __forceinline__ void gll16(const ushort_t* g, ushort_t* l){
    __builtin_amdgcn_global_load_lds(
        (const __attribute__((address_space(1))) unsigned int*)g,
        (__attribute__((address_space(3))) unsigned int*)l,
        16, 0, 0);
}

// ---------------- CSR build ----------------

// zero degree array + the 1KB zero-row page used for edge padding
__global__ void k_zero(int* __restrict__ deg, uint_t* __restrict__ zp){
    int i = blockIdx.x * 256 + threadIdx.x;
    if (i < N_NODES) deg[i] = 0;
    if (i < 256) zp[i] = 0u;
}

__global__ void k_degree(const int* __restrict__ dst, int* __restrict__ deg){
    int e = blockIdx.x * 256 + threadIdx.x;
    if (e < N_EDGES) atomicAdd(&deg[dst[e]], 1);
}

// 256 threads, 40 elems/thread serial scan in regs + 8-round block scan.
__global__ void k_scan(const int* __restrict__ deg, int* __restrict__ row_ptr,
                       int* __restrict__ cursor){
    __shared__ int part[256];
    int t = threadIdx.x;
    int base = t * 40;
    int loc[40];
    int s = 0;
    #pragma unroll
    for (int i = 0; i < 40; ++i){
        int idx = base + i;
        int v = (idx < N_NODES) ? deg[idx] : 0;
        s += v; loc[i] = s;          // thread-local inclusive
    }
    part[t] = s;
    __syncthreads();
    int val = s;
    for (int off = 1; off < 256; off <<= 1){
        int x = (t >= off) ? part[t - off] : 0;
        __syncthreads();
        val += x; part[t] = val;
        __syncthreads();
    }
    int exc = val - s;               // exclusive prefix of this thread's chunk
    if (t == 0) row_ptr[0] = 0;
    int run = exc;
    #pragma unroll
    for (int i = 0; i < 40; ++i){
        int idx = base + i;
        if (idx < N_NODES){
            row_ptr[idx + 1] = exc + loc[i];
            cursor[idx] = run;       // bucket start (exclusive)
        }
        run = exc + loc[i];
    }
}

__global__ void k_scatter(const int* __restrict__ src, const int* __restrict__ dst,
                          int* __restrict__ cursor, int* __restrict__ srcs){
    int e = blockIdx.x * 256 + threadIdx.x;
    if (e < N_EDGES){
        int p = atomicAdd(&cursor[dst[e]], 1);
        srcs[p] = src[e];
    }
}

// ---------------- weight f32 -> bf16 conversion (once per call) ----------------
// job 7 has a second source: d = f2b(s + s2)  (Wsr2 = Ws2 + Wr2, exact f32 add)

struct CvtArgs { const float* s[8]; const float* s2[8]; ushort_t* d[8]; int n[8]; };

__global__ void k_cvt(CvtArgs a){
    int m = blockIdx.y;
    int i = (blockIdx.x * 256 + threadIdx.x) * 8;
    if (i < a.n[m]){
        const float* sp = a.s[m] + i;
        float4 f0 = *(const float4*)sp;
        float4 f1 = *(const float4*)(sp + 4);
        if (a.s2[m]){
            const float* sq = a.s2[m] + i;
            float4 g0 = *(const float4*)sq;
            float4 g1 = *(const float4*)(sq + 4);
            f0.x += g0.x; f0.y += g0.y; f0.z += g0.z; f0.w += g0.w;
            f1.x += g1.x; f1.y += g1.y; f1.z += g1.z; f1.w += g1.w;
        }
        uint4 u;
        u.x = (uint_t)f2b(f0.x) | ((uint_t)f2b(f0.y) << 16);
        u.y = (uint_t)f2b(f0.z) | ((uint_t)f2b(f0.w) << 16);
        u.z = (uint_t)f2b(f1.x) | ((uint_t)f2b(f1.y) << 16);
        u.w = (uint_t)f2b(f1.z) | ((uint_t)f2b(f1.w) << 16);
        *(uint4*)&a.d[m][i] = u;
    }
}

// ---------------- pe = w_pe^T + b_pe (LDS tile transpose, f32 -> bf16) ----------------

__global__ void k_pe(const float* __restrict__ w_pe, const float* __restrict__ b_pe,
                     ushort_t* __restrict__ h0){
    __shared__ float lt[64][68];  // [n_local][i_local], padded
    int t = threadIdx.x;
    int n0 = blockIdx.x * 64, i0 = blockIdx.y * 64;
    int nc = (t & 15) * 4, ir = t >> 4;   // ir 0..15
    #pragma unroll
    for (int p = 0; p < 4; ++p){
        int i_loc = ir + p * 16;
        float4 v = {0.f, 0.f, 0.f, 0.f};
        if (n0 + nc < N_NODES)
            v = *(const float4*)&w_pe[(size_t)(i0 + i_loc) * N_NODES + n0 + nc];
        lt[nc + 0][i_loc] = v.x;
        lt[nc + 1][i_loc] = v.y;
        lt[nc + 2][i_loc] = v.z;
        lt[nc + 3][i_loc] = v.w;
    }
    __syncthreads();
    int ic = t & 7, nr = t >> 3;   // nr 0..31
    #pragma unroll
    for (int p = 0; p < 2; ++p){
        int n_loc = nr + p * 32;
        int n = n0 + n_loc;
        if (n < N_NODES){
            uint4 u;
            uint_t w01 = (uint_t)f2b(lt[n_loc][ic*8+0] + b_pe[i0+ic*8+0])
                       | ((uint_t)f2b(lt[n_loc][ic*8+1] + b_pe[i0+ic*8+1]) << 16);
            uint_t w23 = (uint_t)f2b(lt[n_loc][ic*8+2] + b_pe[i0+ic*8+2])
                       | ((uint_t)f2b(lt[n_loc][ic*8+3] + b_pe[i0+ic*8+3]) << 16);
            uint_t w45 = (uint_t)f2b(lt[n_loc][ic*8+4] + b_pe[i0+ic*8+4])
                       | ((uint_t)f2b(lt[n_loc][ic*8+5] + b_pe[i0+ic*8+5]) << 16);
            uint_t w67 = (uint_t)f2b(lt[n_loc][ic*8+6] + b_pe[i0+ic*8+6])
                       | ((uint_t)f2b(lt[n_loc][ic*8+7] + b_pe[i0+ic*8+7]) << 16);
            u.x = w01; u.y = w23; u.z = w45; u.w = w67;
            *(uint4*)&h0[(size_t)n * DIN + i0 + ic * 8] = u;
        }
    }
}

// ---------------- mean aggregation v6: readlane, 64-edge superblock ------------
// grid (2500, 4): blockIdx.y = 128-dim panel (2.56MB < 4MB per-XCD L2).
// wave = one node; lane covers 2 dims (4B). ONE 256B index load per superblock,
// per-edge index extracted with v_readlane. Tail padded with `dummy` zero row.

#define AGG_EDGE(e, CH) { \
    int s_ = __builtin_amdgcn_readlane(sr, (e)); \
    uint_t v_ = *(const uint_t*)&X[((size_t)(uint_t)s_ << 9) + col]; \
    CH##0 += blo(v_); CH##1 += bhi(v_); }

__global__ __launch_bounds__(256) void k_agg(
    const ushort_t* __restrict__ X, const int* __restrict__ row_ptr,
    const int* __restrict__ srcs, ushort_t* __restrict__ out, int dummy)
{
    int w = threadIdx.x >> 6, lane = threadIdx.x & 63;
    int n = blockIdx.x * 4 + w;
    int col = blockIdx.y * 128 + lane * 2;
    int beg = row_ptr[n], end = row_ptr[n + 1];
    int deg = end - beg;
    float a0=0.f,a1=0.f, p0=0.f,p1=0.f, c0=0.f,c1=0.f, d0=0.f,d1=0.f;

    for (int base = beg; base < end; base += 64){
        int rem = end - base;
        int sr = (lane < rem) ? srcs[base + lane] : dummy;
        int cnt = rem < 64 ? rem : 64;
        #pragma unroll
        for (int k = 0; k < 4; ++k){
            if (k * 16 < cnt){
                int L = k * 16;
                AGG_EDGE(L + 0,  a) AGG_EDGE(L + 1,  p) AGG_EDGE(L + 2,  c) AGG_EDGE(L + 3,  d)
                AGG_EDGE(L + 4,  a) AGG_EDGE(L + 5,  p) AGG_EDGE(L + 6,  c) AGG_EDGE(L + 7,  d)
                AGG_EDGE(L + 8,  a) AGG_EDGE(L + 9,  p) AGG_EDGE(L + 10, c) AGG_EDGE(L + 11, d)
                AGG_EDGE(L + 12, a) AGG_EDGE(L + 13, p) AGG_EDGE(L + 14, c) AGG_EDGE(L + 15, d)
            }
        }
    }

    float r0 = (a0 + p0) + (c0 + d0);
    float r1 = (a1 + p1) + (c1 + d1);
    float inv = (deg > 0) ? 1.f / (float)deg : 1.f;
    uint_t o = (uint_t)f2b(r0 * inv) | ((uint_t)f2b(r1 * inv) << 16);
    *(uint_t*)&out[(size_t)n * 512 + col] = o;
}

// ---------------- final aggregation: fin = Q + mean_agg(P) ----------------
// Uses agg∘matmul commutativity: agg(X)@Wn2^T = agg(X@Wn2^T). P rows are 256
// bf16 (512B). grid (2500, 2): 128-dim panels (2.56MB, L2-resident). Reads Q
// f32 in-place from mid2, writes fin and mid2 (each thread owns its element).

#define AGGF_EDGE(e, CH) { \
    int s_ = __builtin_amdgcn_readlane(sr, (e)); \
    uint_t v_ = *(const uint_t*)&P[((size_t)(uint_t)s_ << 8) + col]; \
    CH##0 += blo(v_); CH##1 += bhi(v_); }

__global__ __launch_bounds__(256) void k_aggf(
    const ushort_t* __restrict__ P, const int* __restrict__ row_ptr,
    const int* __restrict__ srcs, const float* __restrict__ Q,
    float* __restrict__ fin, float* __restrict__ mid2, int dummy)
{
    int w = threadIdx.x >> 6, lane = threadIdx.x & 63;
    int n = blockIdx.x * 4 + w;
    int col = blockIdx.y * 128 + lane * 2;
    int beg = row_ptr[n], end = row_ptr[n + 1];
    int deg = end - beg;
    float a0=0.f,a1=0.f, p0=0.f,p1=0.f, c0=0.f,c1=0.f, d0=0.f,d1=0.f;

    for (int base = beg; base < end; base += 64){
        int rem = end - base;
        int sr = (lane < rem) ? srcs[base + lane] : dummy;
        int cnt = rem < 64 ? rem : 64;
        #pragma unroll
        for (int k = 0; k < 4; ++k){
            if (k * 16 < cnt){
                int L = k * 16;
                AGGF_EDGE(L + 0,  a) AGGF_EDGE(L + 1,  p) AGGF_EDGE(L + 2,  c) AGGF_EDGE(L + 3,  d)
                AGGF_EDGE(L + 4,  a) AGGF_EDGE(L + 5,  p) AGGF_EDGE(L + 6,  c) AGGF_EDGE(L + 7,  d)
                AGGF_EDGE(L + 8,  a) AGGF_EDGE(L + 9,  p) AGGF_EDGE(L + 10, c) AGGF_EDGE(L + 11, d)
                AGGF_EDGE(L + 12, a) AGGF_EDGE(L + 13, p) AGGF_EDGE(L + 14, c) AGGF_EDGE(L + 15, d)
            }
        }
    }

    float r0 = (a0 + p0) + (c0 + d0);
    float r1 = (a1 + p1) + (c1 + d1);
    float inv = (deg > 0) ? 1.f / (float)deg : 1.f;
    float2 q = *(const float2*)&Q[(size_t)n * 256 + col];
    float2 o;
    o.x = q.x + r0 * inv;
    o.y = q.y + r1 * inv;
    *(float2*)&fin [(size_t)n * 256 + col] = o;
    *(float2*)&mid2[(size_t)n * 256 + col] = o;
}

// ---------------- fused SAGE layer (layers 0/1): one-batch BM=160, BN=64 --------
// Y(f32) = leaky(X@Ws^T + Agg@Wn^T + b) + X@Wr^T + rb ; bf16 shadow to YB

template<int DO, int BN, bool ACT, bool WRITE_BF>
__global__ __launch_bounds__(256, 2) void k_layer(
    const ushort_t* __restrict__ X, const ushort_t* __restrict__ G,
    const ushort_t* __restrict__ Ws, const ushort_t* __restrict__ Wn,
    const ushort_t* __restrict__ Wr,
    const float* __restrict__ b, const float* __restrict__ rb,
    float* __restrict__ Y, ushort_t* __restrict__ YB)
{
    constexpr int BM   = 160;
    constexpr int NT   = DO / BN;          // n-tiles
    constexpr int WTN  = BN / 32;          // n-MFMA blocks per wave
    constexpr int NCH  = (2 * BM + 3 * BN) / 16;   // 1KB staging chunks
    constexpr int CHPW = (NCH + 3) / 4;            // chunks per wave
    constexpr int OG   = BM * 32;                  // ushort offsets
    constexpr int OS   = 2 * BM * 32;
    constexpr int WS32 = BN * 32;
    constexpr int BUFSZ = OS + 3 * WS32;
    __shared__ __align__(16) ushort_t smem[2][BUFSZ];

    int t = threadIdx.x;
    int bid = blockIdx.x;
    int r8 = bid & 7, q8 = bid >> 3;
    int m_t = (q8 / NT) * 8 + r8;
    int n_t = q8 % NT;
    if (m_t * BM >= N_NODES) return;
    int m0 = m_t * BM, n0 = n_t * BN;

    int lane = t & 63, w = t >> 6;
    int wr = w >> 1, wc = w & 1;

    const ushort_t* gptr[CHPW];
    int coff[CHPW];
    bool gv[CHPW];
    int rl = lane >> 2, sl = (lane & 3) * 8;
    #pragma unroll
    for (int i = 0; i < CHPW; ++i){
        int qq = w * CHPW + i;
        gv[i] = (qq < NCH);
        int qc = gv[i] ? qq : 0;
        const ushort_t* gA; int rowbase, off;
        if (qc < 10)      { gA = X;  rowbase = m0 + qc * 16;        off = qc * 512; }
        else if (qc < 20) { gA = G;  rowbase = m0 + (qc - 10) * 16; off = OG + (qc - 10) * 512; }
        else {
            int q2 = qc - 20;
            int sec = q2 / (BN / 16), wi = q2 % (BN / 16);
            gA = (sec == 0) ? Ws : (sec == 1) ? Wn : Wr;
            rowbase = n0 + wi * 16;
            off = OS + sec * WS32 + wi * 512;
        }
        gptr[i] = gA + (size_t)(rowbase + rl) * 512 + sl;
        coff[i] = off;
    }

    f32x4 accS[5][WTN] = {}, accG[5][WTN] = {}, accR[5][WTN] = {};
    int r16 = lane & 15;
    int arow = wr * 80 + r16;
    int brow = wc * (BN / 2) + r16;
    int kk = (lane >> 4) * 8;

    #pragma unroll
    for (int i = 0; i < CHPW; ++i) if (gv[i]) gll16(gptr[i], &smem[0][coff[i]]);
    __syncthreads();

    int cur = 0;
    for (int ks = 0; ks < 16; ++ks){
        if (ks < 15){
            int k0 = (ks + 1) * 32;
            #pragma unroll
            for (int i = 0; i < CHPW; ++i) if (gv[i]) gll16(gptr[i] + k0, &smem[cur ^ 1][coff[i]]);
        }

        const ushort_t* sb = smem[cur];
        bf16x8 ax[5], ag[5], bs[WTN], bn_[WTN], brr[WTN];
        #pragma unroll
        for (int m = 0; m < 5; ++m){
            ax[m] = *(const bf16x8*)&sb[(arow + m * 16) * 32 + kk];
            ag[m] = *(const bf16x8*)&sb[OG + (arow + m * 16) * 32 + kk];
        }
        #pragma unroll
        for (int n = 0; n < WTN; ++n){
            bs[n]  = *(const bf16x8*)&sb[OS            + (brow + n * 16) * 32 + kk];
            bn_[n] = *(const bf16x8*)&sb[OS + WS32     + (brow + n * 16) * 32 + kk];
            brr[n] = *(const bf16x8*)&sb[OS + 2 * WS32 + (brow + n * 16) * 32 + kk];
        }
        #pragma unroll
        for (int m = 0; m < 5; ++m)
            #pragma unroll
            for (int n = 0; n < WTN; ++n){
                accS[m][n] = __builtin_amdgcn_mfma_f32_16x16x32_bf16(ax[m], bs[n],  accS[m][n], 0, 0, 0);
                accG[m][n] = __builtin_amdgcn_mfma_f32_16x16x32_bf16(ag[m], bn_[n], accG[m][n], 0, 0, 0);
                accR[m][n] = __builtin_amdgcn_mfma_f32_16x16x32_bf16(ax[m], brr[n], accR[m][n], 0, 0, 0);
            }

        __syncthreads();
        cur ^= 1;
    }

    int col_l = lane & 15;
    int row_l = (lane >> 4) * 4;
    #pragma unroll
    for (int n = 0; n < WTN; ++n){
        int col = n0 + wc * (BN / 2) + n * 16 + col_l;
        float bb = b[col], rbb = rb[col];
        #pragma unroll
        for (int m = 0; m < 5; ++m){
            #pragma unroll
            for (int j = 0; j < 4; ++j){
                int row = m0 + wr * 80 + m * 16 + row_l + j;
                if (row < N_NODES){
                    float v = accS[m][n][j] + accG[m][n][j] + bb;
                    if (ACT) v = (v > 0.f) ? v : 0.01f * v;
                    v += accR[m][n][j] + rbb;
                    Y[(size_t)row * DO + col] = v;
                    if (WRITE_BF) YB[(size_t)row * DO + col] = f2b(v);
                }
            }
        }
    }
}

// ---------------- layer 2 GEMM: P = X@Wn2^T (bf16), Q = X@Wsr2^T + (b2+rb2) (f32) --
// BM=160, BN=32 (504 jobs -> full one-batch residency); 2 products; 28KB LDS.

__global__ __launch_bounds__(256, 2) void k_layer2(
    const ushort_t* __restrict__ X,
    const ushort_t* __restrict__ Wn, const ushort_t* __restrict__ Wsr,
    const float* __restrict__ b, const float* __restrict__ rb,
    ushort_t* __restrict__ Pout, float* __restrict__ Qout)
{
    constexpr int BM = 160, BN = 32, NT = DOUT / BN;   // NT = 8
    constexpr int NCH = 10 + 2 * (BN / 16);            // 14
    constexpr int CHPW = 4;
    constexpr int OWN = BM * 32;                       // 5120
    constexpr int OWS = OWN + BN * 32;                 // 6144
    constexpr int BUFSZ = OWS + BN * 32;               // 7168 ushorts
    __shared__ __align__(16) ushort_t smem[2][BUFSZ];

    int t = threadIdx.x;
    int bid = blockIdx.x;
    int r8 = bid & 7, q8 = bid >> 3;
    int m_t = (q8 / NT) * 8 + r8;
    int n_t = q8 % NT;
    if (m_t * BM >= N_NODES) return;
    int m0 = m_t * BM, n0 = n_t * BN;

    int lane = t & 63, w = t >> 6;
    int wr = w >> 1, wc = w & 1;    // wave tile 80 x 16

    const ushort_t* gptr[CHPW];
    int coff[CHPW];
    bool gv[CHPW];
    int rl = lane >> 2, sl = (lane & 3) * 8;
    #pragma unroll
    for (int i = 0; i < CHPW; ++i){
        int qq = w * CHPW + i;
        gv[i] = (qq < NCH);
        int qc = gv[i] ? qq : 0;
        const ushort_t* gA; int rowbase, off;
        if (qc < 10)      { gA = X;   rowbase = m0 + qc * 16;        off = qc * 512; }
        else if (qc < 12) { gA = Wn;  rowbase = n0 + (qc - 10) * 16; off = OWN + (qc - 10) * 512; }
        else              { gA = Wsr; rowbase = n0 + (qc - 12) * 16; off = OWS + (qc - 12) * 512; }
        gptr[i] = gA + (size_t)(rowbase + rl) * 512 + sl;
        coff[i] = off;
    }

    f32x4 accP[5] = {}, accQ[5] = {};
    int r16 = lane & 15;
    int arow = wr * 80 + r16;
    int brow = wc * 16 + r16;
    int kk = (lane >> 4) * 8;

    #pragma unroll
    for (int i = 0; i < CHPW; ++i) if (gv[i]) gll16(gptr[i], &smem[0][coff[i]]);
    __syncthreads();

    int cur = 0;
    for (int ks = 0; ks < 16; ++ks){
        if (ks < 15){
            int k0 = (ks + 1) * 32;
            #pragma unroll
            for (int i = 0; i < CHPW; ++i) if (gv[i]) gll16(gptr[i] + k0, &smem[cur ^ 1][coff[i]]);
        }

        const ushort_t* sb = smem[cur];
        bf16x8 ax[5];
        #pragma unroll
        for (int m = 0; m < 5; ++m)
            ax[m] = *(const bf16x8*)&sb[(arow + m * 16) * 32 + kk];
        bf16x8 bn_ = *(const bf16x8*)&sb[OWN + brow * 32 + kk];
        bf16x8 bsr = *(const bf16x8*)&sb[OWS + brow * 32 + kk];
        #pragma unroll
        for (int m = 0; m < 5; ++m){
            accP[m] = __builtin_amdgcn_mfma_f32_16x16x32_bf16(ax[m], bn_, accP[m], 0, 0, 0);
            accQ[m] = __builtin_amdgcn_mfma_f32_16x16x32_bf16(ax[m], bsr, accQ[m], 0, 0, 0);
        }

        __syncthreads();
        cur ^= 1;
    }

    int col_l = lane & 15;
    int row_l = (lane >> 4) * 4;
    int col = n0 + wc * 16 + col_l;
    float bb = b[col] + rb[col];
    #pragma unroll
    for (int m = 0; m < 5; ++m){
        #pragma unroll
        for (int j = 0; j < 4; ++j){
            int row = m0 + wr * 80 + m * 16 + row_l + j;
            if (row < N_NODES){
                Qout[(size_t)row * DOUT + col] = accQ[m][j] + bb;
                Pout[(size_t)row * DOUT + col] = f2b(accP[m][j]);
            }
        }
    }
}

// ---------------- launch ----------------

extern "C" void kernel_launch(void* const* d_in, const int* in_sizes, int n_in,
                              void* d_out, int out_size, void* d_ws, size_t ws_size,
                              hipStream_t stream) {
    const int* edge  = (const int*)d_in[0];
    const int* e_src = edge;
    const int* e_dst = edge + N_EDGES;
    const float* w_pe = (const float*)d_in[1];
    const float* b_pe = (const float*)d_in[2];
    const float* ws0 = (const float*)d_in[3];
    const float* wn0 = (const float*)d_in[4];
    const float* b0  = (const float*)d_in[5];
    const float* wr0 = (const float*)d_in[6];
    const float* rb0 = (const float*)d_in[7];
    const float* ws1 = (const float*)d_in[8];
    const float* wn1 = (const float*)d_in[9];
    const float* b1  = (const float*)d_in[10];
    const float* wr1 = (const float*)d_in[11];
    const float* rb1 = (const float*)d_in[12];
    const float* ws2 = (const float*)d_in[13];
    const float* wn2 = (const float*)d_in[14];
    const float* b2  = (const float*)d_in[15];
    const float* wr2 = (const float*)d_in[16];
    const float* rb2 = (const float*)d_in[17];

    char* wsb = (char*)d_ws;
    ushort_t* h0   = (ushort_t*)wsb;                       // 10,240,000 B @ 0
    ushort_t* hb   = (ushort_t*)(wsb + 10240000);          // 10,240,000 B
    ushort_t* aggb = (ushort_t*)(wsb + 20480000);          // 10,240,000 B (pb aliases)
    ushort_t* wbf  = (ushort_t*)(wsb + 30720000);          // 3,932,160 B
    int* deg     = (int*)(wsb + 34652160);                 // 10016 ints
    int* row_ptr = deg + 10016;
    int* cursor  = row_ptr + 10016;
    int* srcs    = cursor + 10016;                         // 320000 ints -> ends 36,052,352
    uint_t* zp   = (uint_t*)(wsb + 36052992);              // 1KB zero row (1024-aligned)
    // dummy row indices relative to each gather base
    const int dummy_h0 = 35208;   // (36052992 - 0) / 1024          (1KB rows)
    const int dummy_hb = 25208;   // (36052992 - 10240000) / 1024   (1KB rows)
    const int dummy_pb = 30416;   // (36052992 - 20480000) / 512    (512B rows)

    ushort_t* wbf0s = wbf;
    ushort_t* wbf0n = wbf + 262144;
    ushort_t* wbf0r = wbf + 524288;
    ushort_t* wbf1s = wbf + 786432;
    ushort_t* wbf1n = wbf + 1048576;
    ushort_t* wbf1r = wbf + 1310720;
    ushort_t* wbf2n = wbf + 1572864;   // Wn2
    ushort_t* wbf2sr= wbf + 1703936;   // Ws2 + Wr2

    float* out  = (float*)d_out;
    float* fin  = out;               // [10000][256]
    float* mid0 = out + 2560000;     // [10000][512]
    float* mid1 = out + 7680000;     // [10000][512]
    float* mid2 = out + 12800000;    // [10000][256]
    ushort_t* pb = aggb;             // P = X@Wn2^T, bf16 [10000][256]

    k_zero   <<<40, 256, 0, stream>>>(deg, zp);
    k_degree <<<1250, 256, 0, stream>>>(e_dst, deg);
    k_scan   <<<1, 256, 0, stream>>>(deg, row_ptr, cursor);
    k_scatter<<<1250, 256, 0, stream>>>(e_src, e_dst, cursor, srcs);

    CvtArgs ca;
    ca.s[0]=ws0; ca.s[1]=wn0; ca.s[2]=wr0;
    ca.s[3]=ws1; ca.s[4]=wn1; ca.s[5]=wr1;
    ca.s[6]=wn2; ca.s[7]=ws2;
    for (int i = 0; i < 8; ++i) ca.s2[i] = nullptr;
    ca.s2[7] = wr2;                                  // Wsr2 = Ws2 + Wr2
    ca.d[0]=wbf0s; ca.d[1]=wbf0n; ca.d[2]=wbf0r;
    ca.d[3]=wbf1s; ca.d[4]=wbf1n; ca.d[5]=wbf1r;
    ca.d[6]=wbf2n; ca.d[7]=wbf2sr;
    for (int i = 0; i < 6; ++i) ca.n[i] = 262144;
    ca.n[6] = 131072; ca.n[7] = 131072;
    k_cvt<<<dim3(128, 8), 256, 0, stream>>>(ca);

    k_pe<<<dim3(157, 8), 256, 0, stream>>>(w_pe, b_pe, h0);

    k_agg<<<dim3(2500, 4), 256, 0, stream>>>(h0, row_ptr, srcs, aggb, dummy_h0);
    k_layer<512, 64, true, true ><<<dim3(512), 256, 0, stream>>>(
        h0, aggb, wbf0s, wbf0n, wbf0r, b0, rb0, mid0, hb);

    k_agg<<<dim3(2500, 4), 256, 0, stream>>>(hb, row_ptr, srcs, aggb, dummy_hb);
    k_layer<512, 64, true, true ><<<dim3(512), 256, 0, stream>>>(
        hb, aggb, wbf1s, wbf1n, wbf1r, b1, rb1, mid1, h0);

    // layer 2 via agg-commute: P = X@Wn2^T, Q = X@(Ws2+Wr2)^T + (b2+rb2);
    // fin = mid2 = Q + mean_agg(P)
    k_layer2<<<dim3(512), 256, 0, stream>>>(h0, wbf2n, wbf2sr, b2, rb2, pb, mid2);
    k_aggf<<<dim3(2500, 2), 256, 0, stream>>>(pb, row_ptr, srcs, mid2, fin, mid2, dummy_pb);
}